// Round 14
// baseline (36.907 us; speedup 1.0000x reference)
//
#include <hip/hip_runtime.h>

#define SEQ 128
#define SD  15
#define REC 32    // floats per (b,s) record in dba_params
#define WPB 4     // waves per block, ONE ROW PER WAVE
#define NT  (WPB * 64)   // 256 threads

// ---------------------------------------------------------------------------
// R13 = R12's barrier-free wave-per-row skeleton
//     + R5's store placement (bulk stores pre-chain = hidden; quat-only tail)
//     + full residency (16.5 KB LDS, <=64 VGPR -> 8 blocks/CU = 32 waves/CU).
//  - lane l owns records 2l, 2l+1; pair-sum shuffle scan gives positions.
//  - pos + zeros + (lane0) t=0 quat stored IMMEDIATELY post-scan: they drain
//    under the chip-wide load burst (R5's empirically-winning placement).
//  - lane 0 runs the 127-step chain from the wave's LDS dq region through a
//    4-deep double-buffered named-register window (32 VGPR), quats -> LDS.
//  - only the 4-float quat stores are exposed post-fence; they merge into
//    the still-dirty L2 lines written by the early stores.
// No __syncthreads anywhere — only wave-internal s_waitcnt fences.
// ---------------------------------------------------------------------------
__global__ __launch_bounds__(NT, 8) void fused_kernel(const float* __restrict__ dba,
                                                      const float* __restrict__ gt,
                                                      float* __restrict__ out,
                                                      int B) {
    const int tid  = threadIdx.x;
    const int wave = tid >> 6;
    const int lane = tid & 63;
    const int r    = blockIdx.x * WPB + wave;
    if (r >= B) return;                       // wave-uniform exit

    __shared__ float4 sdq  [WPB][SEQ + 1];    // 8.25 KB: pre-scaled dq
    __shared__ float4 squat[WPB][SEQ + 1];    // 8.25 KB: chain output

    // ---- loads: gt head first (feeds chain + pos), then 2 records/lane ----
    const float* g  = gt + (size_t)r * SEQ * SD;           // row-aligned line
    const float4 gA = *reinterpret_cast<const float4*>(g);      // px,py,pz,q0
    const float4 gB = *reinterpret_cast<const float4*>(g + 4);  // q1,q2,q3,·

    const float* rec0 = dba + ((size_t)r * SEQ + 2 * lane) * REC;
    const float4 h0a = *reinterpret_cast<const float4*>(rec0);
    const float4 h0b = *reinterpret_cast<const float4*>(rec0 + 4);
    const float4 h1a = *reinterpret_cast<const float4*>(rec0 + REC);
    const float4 h1b = *reinterpret_cast<const float4*>(rec0 + REC + 4);

    sdq[wave][2 * lane]     = make_float4(h0a.w * 0.1f, h0b.x * 0.1f,
                                          h0b.y * 0.1f, h0b.z * 0.1f);
    sdq[wave][2 * lane + 1] = make_float4(h1a.w * 0.1f, h1b.x * 0.1f,
                                          h1b.y * 0.1f, h1b.z * 0.1f);

    const float d0x = h0a.x * 0.1f, d0y = h0a.y * 0.1f, d0z = h0a.z * 0.1f;
    const float d1x = h1a.x * 0.1f, d1y = h1a.y * 0.1f, d1z = h1a.z * 0.1f;

    // ---- wave scan of per-lane pair sums ----
    const float sx = d0x + d1x, sy = d0y + d1y, sz = d0z + d1z;
    float ix = sx, iy = sy, iz = sz;
#pragma unroll
    for (int off = 1; off < 64; off <<= 1) {
        const float tx = __shfl_up(ix, off, 64);
        const float ty = __shfl_up(iy, off, 64);
        const float tz = __shfl_up(iz, off, 64);
        if (lane >= off) { ix += tx; iy += ty; iz += tz; }
    }
    const float ex = ix - sx, ey = iy - sy, ez = iz - sz;  // prefix < rec 2l

    // ---- EARLY stores: pos + zeros (+ lane0: t=0 quat) — hide under burst ----
    float* o0 = out + ((size_t)r * SEQ + 2 * lane) * SD;
    o0[0] = gA.x + ex; o0[1] = gA.y + ey; o0[2] = gA.z + ez;
    if (lane == 0) {                          // t=0 quat: init_q, NOT normalized
        o0[3] = gA.w; o0[4] = gB.x; o0[5] = gB.y; o0[6] = gB.z;
    }
#pragma unroll
    for (int k = 7; k < SD; ++k) o0[k] = 0.f;
    float* o1 = o0 + SD;
    o1[0] = gA.x + ex + d0x; o1[1] = gA.y + ey + d0y; o1[2] = gA.z + ez + d0z;
#pragma unroll
    for (int k = 7; k < SD; ++k) o1[k] = 0.f;

    // wave-internal fence: all lanes' sdq writes visible to lane 0
    asm volatile("s_waitcnt lgkmcnt(0)" ::: "memory");

    // ---- chain: lane 0, 4-deep double window (32 VGPR), quats -> LDS ----
    if (lane == 0) {
        const float4* srow = sdq[wave];
        float4*       qrow = squat[wave];
        float q0 = gA.w, q1 = gB.x, q2 = gB.y, q3 = gB.z;

#define QSTEP(C, T) do {                                                \
            q0 += (C).x; q1 += (C).y; q2 += (C).z; q3 += (C).w;         \
            const float a_ = q0 * q0 + q1 * q1;                         \
            const float b_ = q2 * q2 + q3 * q3;                         \
            const float i_ = __builtin_amdgcn_rsqf(a_ + b_);            \
            q0 *= i_; q1 *= i_; q2 *= i_; q3 *= i_;                     \
            qrow[T] = make_float4(q0, q1, q2, q3);                      \
        } while (0)

        float4 c0 = srow[0], c1 = srow[1], c2 = srow[2], c3 = srow[3];
        for (int w = 0; w < 31; ++w) {               // t = 1..124
            const float4* nx = srow + (w + 1) * 4;   // last: srow[124..127]
            const float4 n0 = nx[0], n1 = nx[1], n2 = nx[2], n3 = nx[3];
            const int t = w * 4 + 1;
            QSTEP(c0, t); QSTEP(c1, t + 1); QSTEP(c2, t + 2); QSTEP(c3, t + 3);
            c0 = n0; c1 = n1; c2 = n2; c3 = n3;
        }
        QSTEP(c0, 125); QSTEP(c1, 126); QSTEP(c2, 127);
#undef QSTEP
    }

    // wave-internal fence: lane 0's quat writes visible to all lanes
    asm volatile("s_waitcnt lgkmcnt(0)" ::: "memory");

    // ---- exposed tail: quat stores only (merge into L2-dirty lines) ----
    if (lane > 0) {
        const float4 q = squat[wave][2 * lane];
        o0[3] = q.x; o0[4] = q.y; o0[5] = q.z; o0[6] = q.w;
    }
    {
        const float4 q = squat[wave][2 * lane + 1];
        o1[3] = q.x; o1[4] = q.y; o1[5] = q.z; o1[6] = q.w;
    }
}

extern "C" void kernel_launch(void* const* d_in, const int* in_sizes, int n_in,
                              void* d_out, int out_size, void* d_ws, size_t ws_size,
                              hipStream_t stream) {
    const float* dba = (const float*)d_in[0];   // (B, 128, 32)
    // d_in[1] = imu_measurements — unused by the reference
    const float* gt  = (const float*)d_in[2];   // (B, 128, 15)
    float* out = (float*)d_out;                 // (B, 128, 15)

    const int B = in_sizes[0] / (SEQ * REC);
    const int blocks = (B + WPB - 1) / WPB;     // 1024 @ B=4096
    fused_kernel<<<blocks, NT, 0, stream>>>(dba, gt, out, B);
}